// Round 5
// baseline (297.726 us; speedup 1.0000x reference)
//
#include <hip/hip_runtime.h>
#include <math.h>

typedef _Float16 h2 __attribute__((ext_vector_type(2)));

#if __has_builtin(__builtin_amdgcn_fdot2)
#define FDOT2(a,b,c) __builtin_amdgcn_fdot2((a),(b),(c),false)
#else
__device__ __forceinline__ float FDOT2(h2 a, h2 b, float c){
    return c + (float)a.x*(float)b.x + (float)a.y*(float)b.y;
}
#endif

__device__ __forceinline__ h2 pk2(float x, float y){
#if __has_builtin(__builtin_amdgcn_cvt_pkrtz)
    return __builtin_bit_cast(h2, __builtin_amdgcn_cvt_pkrtz(x, y));
#else
    h2 r; r.x = (_Float16)x; r.y = (_Float16)y; return r;
#endif
}
__device__ __forceinline__ unsigned h2u(h2 v){ return __builtin_bit_cast(unsigned, v); }
__device__ __forceinline__ h2 uh2(unsigned v){ return __builtin_bit_cast(h2, v); }

__device__ __forceinline__ float dot8(uint4 w, uint4 v, float acc){
    acc = FDOT2(uh2(w.x), uh2(v.x), acc);
    acc = FDOT2(uh2(w.y), uh2(v.y), acc);
    acc = FDOT2(uh2(w.z), uh2(v.z), acc);
    acc = FDOT2(uh2(w.w), uh2(v.w), acc);
    return acc;
}

__device__ __forceinline__ float gelu_exact(float x){
    return 0.5f * x * (1.0f + erff(x * 0.70710678118654752f));
}
__device__ __forceinline__ float wave_sum64(float v){
    #pragma unroll
    for(int off = 32; off >= 1; off >>= 1) v += __shfl_xor(v, off, 64);
    return v;
}
// same-wave LDS RAW fence: DS ops are in-order per wave; drains lgkm and stops
// compiler reordering LDS accesses across it. No __syncthreads needed.
__device__ __forceinline__ void lds_fence(){ __asm__ volatile("s_waitcnt lgkmcnt(0)" ::: "memory"); }

// ---------------- packed-weight layout in d_ws (dword offsets) ----------------
#define W1T_OFF 0        // [64][44]  fte_w1^T pairs (81 c's, zero-padded)
#define W2T_OFF 2816     // [64][36]  fte_w2 (src [o][c])
#define WQ_OFF  5120     // [64][36]
#define FW1_OFF 7424     // [64][36]
#define FW2_OFF 9728     // [64][36]
#define WV_OFF  12032    // [64][68]
#define WP_OFF  16384    // [64][68]
#define WK_OFF  20736    // [128 c][36]: dword hp = h*4+dp holds pair (wk[c][2hp], wk[c][2hp+1])
#define WTOT    25344    // dwords = 101.4 KB

// per-pixel LDS scratch (dword offsets within a wave's region)
#define CMO   0          // cm_h  [8 j][68]: pairs over c
#define TUO   544        // tu_h / u_h [8 h][68]: pairs over c
#define CORRO 1088       // corr pairs [44]
#define QPO   1132       // generic 64-vec pair buffer [36]
#define CCO   1168       // concat pairs [64]
#define ASO   1232       // attention weights a, f32 [64]
#define PIXDW 1296
#define NWAVE 4
#define LDSDW (WTOT + NWAVE*PIXDW)   // 30528 dw = 122.1 KB

// K0: pack all weight matrices to f16-pair layouts in d_ws.
__global__ void prep_weights(const float* __restrict__ w1, const float* __restrict__ w2,
                             const float* __restrict__ wq, const float* __restrict__ fw1,
                             const float* __restrict__ fw2, const float* __restrict__ wv,
                             const float* __restrict__ wp, const float* __restrict__ wk,
                             unsigned* __restrict__ ws){
    int idx = blockIdx.x * blockDim.x + threadIdx.x;
    if(idx >= WTOT) return;
    float a = 0.f, b = 0.f;
    if(idx < W2T_OFF){                       // W1T [64][44], src w1 [o=64][c=81]
        int t = idx / 44, cp = idx % 44;
        if(2*cp   < 81) a = w1[t*81 + 2*cp];
        if(2*cp+1 < 81) b = w1[t*81 + 2*cp+1];
    } else if(idx < WQ_OFF){                 // W2T [64][36], src w2 [o=64][c=64]
        int r = idx - W2T_OFF; int t = r / 36, cp = r % 36;
        if(cp < 32){ a = w2[t*64 + 2*cp]; b = w2[t*64 + 2*cp+1]; }
    } else if(idx < FW1_OFF){                // WQ [64][36], src wq [c=64][o=64]
        int r = idx - WQ_OFF; int t = r / 36, cp = r % 36;
        if(cp < 32){ a = wq[(2*cp)*64 + t]; b = wq[(2*cp+1)*64 + t]; }
    } else if(idx < FW2_OFF){                // FW1
        int r = idx - FW1_OFF; int t = r / 36, cp = r % 36;
        if(cp < 32){ a = fw1[(2*cp)*64 + t]; b = fw1[(2*cp+1)*64 + t]; }
    } else if(idx < WV_OFF){                 // FW2
        int r = idx - FW2_OFF; int t = r / 36, cp = r % 36;
        if(cp < 32){ a = fw2[(2*cp)*64 + t]; b = fw2[(2*cp+1)*64 + t]; }
    } else if(idx < WP_OFF){                 // WV [64][68], src wv [c=128][o=64]
        int r = idx - WV_OFF; int t = r / 68, cp = r % 68;
        if(cp < 64){ a = wv[(2*cp)*64 + t]; b = wv[(2*cp+1)*64 + t]; }
    } else if(idx < WK_OFF){                 // WP [64][68], src wp [c=128][o=64]
        int r = idx - WP_OFF; int t = r / 68, cp = r % 68;
        if(cp < 64){ a = wp[(2*cp)*64 + t]; b = wp[(2*cp+1)*64 + t]; }
    } else {                                 // WK [128][36], src wk [c=128][o=64]
        int r = idx - WK_OFF; int c = r / 36, hp = r % 36;
        if(hp < 32){ a = wk[c*64 + 2*hp]; b = wk[c*64 + 2*hp+1]; }
    }
    ws[idx] = h2u(pk2(a, b));
}

__device__ __forceinline__ float bilin(const float* __restrict__ cmap, float cx, float cy, int e){
    int i = e / 9, j = e - 9*i;
    float sx = cx + (float)(i - 4);
    float sy = cy + (float)(j - 4);
    float x0 = floorf(sx), y0 = floorf(sy);
    float wx = sx - x0,   wy = sy - y0;
    float acc = 0.f;
    #pragma unroll
    for(int dy = 0; dy < 2; dy++){
        #pragma unroll
        for(int dx = 0; dx < 2; dx++){
            float xf = x0 + (float)dx, yf = y0 + (float)dy;
            bool valid = (xf >= 0.f) && (xf <= 63.f) && (yf >= 0.f) && (yf <= 63.f);
            int xi = min(max((int)xf, 0), 63);
            int yi = min(max((int)yf, 0), 63);
            float v = valid ? cmap[yi*64 + xi] : 0.f;
            acc += v * ((dx ? wx : 1.f - wx) * (dy ? wy : 1.f - wy));
        }
    }
    return acc;
}

// Main kernel: grid=256 x 256 threads (4 waves). Weights staged to LDS once,
// then the 7 hot matrices are register-cached per lane (lane = out dim owns its
// row). 1 wave/SIMD (VGPR-fat waves); 8 sequential pixels per wave.
__global__ __launch_bounds__(256, 1) void decoder_main(
    const float* __restrict__ cost_maps, const float* __restrict__ cost_memory,
    const float* __restrict__ coords1, const unsigned* __restrict__ ws,
    const float* __restrict__ fte_b1, const float* __restrict__ fte_b2,
    const float* __restrict__ ln1_g, const float* __restrict__ ln1_b,
    const float* __restrict__ ln2_g, const float* __restrict__ ln2_b,
    const float* __restrict__ bq, const float* __restrict__ bv,
    const float* __restrict__ bp, const float* __restrict__ fb1,
    const float* __restrict__ fb2, float* __restrict__ out_cg)
{
    __shared__ unsigned sm[LDSDW];

    const int tid = threadIdx.x;
    const int wv  = tid >> 6;
    const int ln  = tid & 63;

    // ---- cooperative weight copy d_ws -> LDS (uint4, coalesced)
    {
        const uint4* src = (const uint4*)ws;
        uint4* dst = (uint4*)sm;
        for(int i = tid; i < WTOT/4; i += 256) dst[i] = src[i];
    }
    const float b1v = fte_b1[ln], b2v = fte_b2[ln];
    const float g1v = ln1_g[ln], be1 = ln1_b[ln];
    const float g2v = ln2_g[ln], be2 = ln2_b[ln];
    const float bqv = bq[ln], bvv = bv[ln], bpv = bp[ln];
    const float f1v = fb1[ln], f2v = fb2[ln];
    __syncthreads();   // the ONLY block-wide barrier

    const int h_ = ln & 7;     // head (producer role)
    const int c0 = ln >> 3;    // c sub-lane (producer role)
    const int j_ = ln >> 3;    // token (K-consumer role)
    const int h3 = ln >> 3;    // head of this output dim

    // ---- register-cache the hot weight rows (lane = out dim / producer role)
    uint4 rW2T[8], rWQ[8], rFW1[8], rFW2[8], rWV[16], rWP[16], rWK[16];
    #pragma unroll
    for(int g = 0; g < 8; g++)  rW2T[g] = *(const uint4*)&sm[W2T_OFF + ln*36 + 4*g];
    #pragma unroll
    for(int g = 0; g < 8; g++)  rWQ[g]  = *(const uint4*)&sm[WQ_OFF  + ln*36 + 4*g];
    #pragma unroll
    for(int g = 0; g < 8; g++)  rFW1[g] = *(const uint4*)&sm[FW1_OFF + ln*36 + 4*g];
    #pragma unroll
    for(int g = 0; g < 8; g++)  rFW2[g] = *(const uint4*)&sm[FW2_OFF + ln*36 + 4*g];
    #pragma unroll
    for(int g = 0; g < 16; g++) rWV[g]  = *(const uint4*)&sm[WV_OFF  + ln*68 + 4*g];
    #pragma unroll
    for(int g = 0; g < 16; g++) rWP[g]  = *(const uint4*)&sm[WP_OFF  + ln*68 + 4*g];
    #pragma unroll
    for(int i = 0; i < 16; i++) rWK[i]  = *(const uint4*)&sm[WK_OFF + (c0 + 8*i)*36 + h_*4];

    unsigned* P = sm + WTOT + wv * PIXDW;
    float*    Pf = (float*)P;

    int pix = blockIdx.x * 32 + wv;
    const float4* cm4p = (const float4*)cost_memory;
    float4 cmv0 = cm4p[(size_t)pix*256 +   0 + ln];
    float4 cmv1 = cm4p[(size_t)pix*256 +  64 + ln];
    float4 cmv2 = cm4p[(size_t)pix*256 + 128 + ln];
    float4 cmv3 = cm4p[(size_t)pix*256 + 192 + ln];
    float cx = coords1[(pix >> 12)*8192 + (pix & 4095)];
    float cy = coords1[(pix >> 12)*8192 + 4096 + (pix & 4095)];

    #pragma unroll 1
    for(int g = 0; g < 8; g++){
        // ---- stage cm pairs into LDS
        {
            float4 v; int l0, jt, cp0;
            #define STAGE(V, I4) \
                v = V; l0 = 4*((I4)*64 + ln); jt = l0 >> 7; cp0 = (l0 & 127) >> 1; \
                P[CMO + jt*68 + cp0]     = h2u(pk2(v.x, v.y)); \
                P[CMO + jt*68 + cp0 + 1] = h2u(pk2(v.z, v.w));
            STAGE(cmv0, 0) STAGE(cmv1, 1) STAGE(cmv2, 2) STAGE(cmv3, 3)
            #undef STAGE
        }
        // ---- bilinear correlation window -> corr pairs
        {
            const float* cmap = cost_maps + (size_t)pix * 4096;
            float cv = bilin(cmap, cx, cy, ln);
            float pr = __shfl_xor(cv, 1, 64);
            if((ln & 1) == 0) P[CORRO + (ln >> 1)] = h2u(pk2(cv, pr));
            float c2 = 0.f;
            if(ln < 17) c2 = bilin(cmap, cx, cy, 64 + ln);
            float pr2 = __shfl_xor(c2, 1, 64);
            if(ln < 17 && (ln & 1) == 0){
                float bb = (ln == 16) ? 0.f : pr2;
                P[CORRO + 32 + (ln >> 1)] = h2u(pk2(c2, bb));
            }
            if(ln < 3) P[CORRO + 41 + ln] = 0u;
        }
        // ---- prefetch next pixel
        int npix = pix + 4;
        float4 n0, n1, n2, n3; float ncx = 0.f, ncy = 0.f;
        if(g < 7){
            n0 = cm4p[(size_t)npix*256 +   0 + ln];
            n1 = cm4p[(size_t)npix*256 +  64 + ln];
            n2 = cm4p[(size_t)npix*256 + 128 + ln];
            n3 = cm4p[(size_t)npix*256 + 192 + ln];
            ncx = coords1[(npix >> 12)*8192 + (npix & 4095)];
            ncy = coords1[(npix >> 12)*8192 + 4096 + (npix & 4095)];
        }
        lds_fence();

        // ---- FTE1: 81->64 + GELU  (W1T stays in LDS; activations uniform)
        float q1a = b1v, q1b = 0.f;
        {
            const uint4* wr = (const uint4*)&sm[W1T_OFF + ln*44];
            const uint4* ar = (const uint4*)&P[CORRO];
            #pragma unroll
            for(int gg = 0; gg < 10; gg += 2){
                q1a = dot8(wr[gg],   ar[gg],   q1a);
                q1b = dot8(wr[gg+1], ar[gg+1], q1b);
            }
            q1a = dot8(wr[10], ar[10], q1a);
        }
        float q1 = gelu_exact(q1a + q1b);
        {
            float pr = __shfl_xor(q1, 1, 64);
            if((ln & 1) == 0) P[QPO + (ln >> 1)] = h2u(pk2(q1, pr));
        }
        lds_fence();
        // ---- FTE2: 64->64
        float sva = b2v, svb = 0.f;
        {
            const uint4* ar = (const uint4*)&P[QPO];
            #pragma unroll
            for(int gg = 0; gg < 8; gg += 2){
                sva = dot8(rW2T[gg],   ar[gg],   sva);
                svb = dot8(rW2T[gg+1], ar[gg+1], svb);
            }
        }
        float shortv = sva + svb;
        // ---- LN1 + position encoding
        float mean = wave_sum64(shortv) * (1.f/64.f);
        float d0   = shortv - mean;
        float var  = wave_sum64(d0*d0) * (1.f/64.f);
        float qn   = d0 * rsqrtf(var + 1e-5f) * g1v + be1;
        {
            int   fi    = ln & 15;
            float coord = (ln < 32) ? cx : cy;
            float ang   = 3.14f * coord * (float)fi / 200.0f;
            float enc   = (ln & 16) ? cosf(ang) : sinf(ang);
            float qv    = qn + enc;
            float pr = __shfl_xor(qv, 1, 64);
            if((ln & 1) == 0) P[QPO + (ln >> 1)] = h2u(pk2(qv, pr));
        }
        lds_fence();
        // ---- Wq
        float qla = bqv, qlb = 0.f;
        {
            const uint4* ar = (const uint4*)&P[QPO];
            #pragma unroll
            for(int gg = 0; gg < 8; gg += 2){
                qla = dot8(rWQ[gg],   ar[gg],   qla);
                qlb = dot8(rWQ[gg+1], ar[gg+1], qlb);
            }
        }
        float qlin = qla + qlb;
        // ---- K path: t[c,h] = sum_d q[h,d] wk[c,h*8+d]  (bk cancels in softmax)
        {
            uint4 qh4 = *(const uint4*)&P[QPO + h_*4];
            #pragma unroll
            for(int i = 0; i < 16; i++){
                float tv = dot8(rWK[i], qh4, 0.f);
                float prt = __shfl_xor(tv, 8, 64);
                if((c0 & 1) == 0) P[TUO + h_*68 + (c0 >> 1) + 4*i] = h2u(pk2(tv, prt));
            }
        }
        lds_fence();
        // s[j,h] = sum_cp dot2(cm[j], t[h])
        float sa = 0.f, sb = 0.f;
        {
            const int hk = ln & 7;
            const uint4* cmr = (const uint4*)&P[CMO + j_*68];
            const uint4* tur = (const uint4*)&P[TUO + hk*68];
            #pragma unroll
            for(int gg = 0; gg < 16; gg += 2){
                sa = dot8(cmr[gg],   tur[gg],   sa);
                sb = dot8(cmr[gg+1], tur[gg+1], sb);
            }
        }
        float sacc = sa + sb;
        // softmax over tokens (lanes ln = j*8+h; reduce over j)
        float sc = sacc * 0.35355339059327373f;
        float mx = sc;
        mx = fmaxf(mx, __shfl_xor(mx,  8, 64));
        mx = fmaxf(mx, __shfl_xor(mx, 16, 64));
        mx = fmaxf(mx, __shfl_xor(mx, 32, 64));
        float ex = expf(sc - mx);
        float se = ex;
        se += __shfl_xor(se,  8, 64);
        se += __shfl_xor(se, 16, 64);
        se += __shfl_xor(se, 32, 64);
        Pf[ASO + ln] = ex / se;
        lds_fence();
        // ---- V path: u[h][c] = sum_j a[j,h] cm[j,c]
        {
            h2 aj2[8];
            #pragma unroll
            for(int j = 0; j < 8; j++){
                float av = Pf[ASO + j*8 + h_];
                aj2[j] = pk2(av, av);
            }
            #pragma unroll
            for(int i = 0; i < 8; i++){
                int cp = c0 + 8*i;
                h2 u2 = pk2(0.f, 0.f);
                #pragma unroll
                for(int j = 0; j < 8; j++)
                    u2 += aj2[j] * uh2(P[CMO + j*68 + cp]);
                P[TUO + h_*68 + cp] = h2u(u2);
            }
        }
        lds_fence();
        // attno = bv + sum_c u[h3][c] wv[c][ln]
        float ata = bvv, atb = 0.f;
        {
            const uint4* ur = (const uint4*)&P[TUO + h3*68];
            #pragma unroll
            for(int gg = 0; gg < 16; gg += 2){
                ata = dot8(ur[gg],   rWV[gg],   ata);
                atb = dot8(ur[gg+1], rWV[gg+1], atb);
            }
        }
        float attno = ata + atb;
        // ---- wp on concat(attno, short) + residual
        {
            float pa = __shfl_xor(attno, 1, 64);
            if((ln & 1) == 0) P[CCO + (ln >> 1)] = h2u(pk2(attno, pa));
            float psv = __shfl_xor(shortv, 1, 64);
            if((ln & 1) == 0) P[CCO + 32 + (ln >> 1)] = h2u(pk2(shortv, psv));
        }
        lds_fence();
        float xa = bpv, xb = 0.f;
        {
            const uint4* ar = (const uint4*)&P[CCO];
            #pragma unroll
            for(int gg = 0; gg < 16; gg += 2){
                xa = dot8(rWP[gg],   ar[gg],   xa);
                xb = dot8(rWP[gg+1], ar[gg+1], xb);
            }
        }
        float x = xa + xb + shortv;
        // ---- LN2 + FFN + residual
        float m2 = wave_sum64(x) * (1.f/64.f);
        float dd = x - m2;
        float v2 = wave_sum64(dd*dd) * (1.f/64.f);
        float xn = dd * rsqrtf(v2 + 1e-5f) * g2v + be2;
        {
            float pr = __shfl_xor(xn, 1, 64);
            if((ln & 1) == 0) P[QPO + (ln >> 1)] = h2u(pk2(xn, pr));
        }
        lds_fence();
        float ha = f1v, hb = 0.f;
        {
            const uint4* ar = (const uint4*)&P[QPO];
            #pragma unroll
            for(int gg = 0; gg < 8; gg += 2){
                ha = dot8(rFW1[gg],   ar[gg],   ha);
                hb = dot8(rFW1[gg+1], ar[gg+1], hb);
            }
        }
        float h1v = gelu_exact(ha + hb);
        {
            float pr = __shfl_xor(h1v, 1, 64);
            if((ln & 1) == 0) P[QPO + (ln >> 1)] = h2u(pk2(h1v, pr));
        }
        lds_fence();
        float fa = f2v, fb = 0.f;
        {
            const uint4* ar = (const uint4*)&P[QPO];
            #pragma unroll
            for(int gg = 0; gg < 8; gg += 2){
                fa = dot8(rFW2[gg],   ar[gg],   fa);
                fb = dot8(rFW2[gg+1], ar[gg+1], fb);
            }
        }
        x += fa + fb;
        // store: cost_global [B,64,64,64]
        {
            int bb = pix >> 12, hh = (pix >> 6) & 63, ww = pix & 63;
            out_cg[(((size_t)(bb*64 + ln))*64 + hh)*64 + ww] = x;
        }
        pix = npix; cx = ncx; cy = ncy;
        cmv0 = n0; cmv1 = n1; cmv2 = n2; cmv3 = n3;
    }
}

// Convex upsampling: block = (b,h,r), 512 threads.
__global__ __launch_bounds__(512) void upsample_kernel(
    const float* __restrict__ coords1, const float* __restrict__ up_mask,
    float* __restrict__ out)
{
    __shared__ float mtile[9 * 544];
    __shared__ float fxs[3 * 64];
    __shared__ float fys[3 * 64];

    const int r = blockIdx.x & 7;
    const int h = (blockIdx.x >> 3) & 63;
    const int b = blockIdx.x >> 9;
    const int id = threadIdx.x;

    {
        const int s_ = id >> 6, w_ = id & 63;
        #pragma unroll
        for(int k = 0; k < 9; k++){
            int c = k*64 + r*8 + s_;
            mtile[k*544 + s_*68 + w_] =
                up_mask[(((size_t)b*576 + c)*64 + h)*64 + w_];
        }
    }
    if(id < 192){
        const int i = id >> 6, w_ = id & 63;
        const int hh = h + i - 1;
        float fx = 0.f, fy = 0.f;
        if(hh >= 0 && hh < 64){
            fx = 8.f * (coords1[((b*2 + 0)*64 + hh)*64 + w_] - (float)w_);
            fy = 8.f * (coords1[((b*2 + 1)*64 + hh)*64 + w_] - (float)hh);
        }
        fxs[i*64 + w_] = fx;
        fys[i*64 + w_] = fy;
    }
    __syncthreads();

    const int w = id >> 3, s = id & 7;
    float m[9];
    #pragma unroll
    for(int k = 0; k < 9; k++) m[k] = mtile[k*544 + s*68 + w];
    float mx = m[0];
    #pragma unroll
    for(int k = 1; k < 9; k++) mx = fmaxf(mx, m[k]);
    float se = 0.f;
    #pragma unroll
    for(int k = 0; k < 9; k++){ m[k] = expf(m[k] - mx); se += m[k]; }
    float inv = 1.f / se;

    float ox = 0.f, oy = 0.f;
    #pragma unroll
    for(int k = 0; k < 9; k++){
        int i = k / 3, j = k % 3;
        int ww = w + j - 1;
        float fx = 0.f, fy = 0.f;
        if(ww >= 0 && ww < 64){
            fx = fxs[i*64 + ww];
            fy = fys[i*64 + ww];
        }
        ox += m[k] * fx;
        oy += m[k] * fy;
    }
    ox *= inv; oy *= inv;

    const size_t row = (size_t)(h*8 + r) * 512 + w*8 + s;
    out[(size_t)(b*2 + 0)*262144 + row] = ox;
    out[(size_t)(b*2 + 1)*262144 + row] = oy;
}

extern "C" void kernel_launch(void* const* d_in, const int* in_sizes, int n_in,
                              void* d_out, int out_size, void* d_ws, size_t ws_size,
                              hipStream_t stream)
{
    const float* cost_maps   = (const float*)d_in[0];
    const float* cost_memory = (const float*)d_in[1];
    const float* coords1     = (const float*)d_in[2];
    const float* up_mask     = (const float*)d_in[3];
    const float* fte_w1      = (const float*)d_in[4];
    const float* fte_b1      = (const float*)d_in[5];
    const float* fte_w2      = (const float*)d_in[6];
    const float* fte_b2      = (const float*)d_in[7];
    const float* ln1_g       = (const float*)d_in[8];
    const float* ln1_b       = (const float*)d_in[9];
    const float* ln2_g       = (const float*)d_in[10];
    const float* ln2_b       = (const float*)d_in[11];
    const float* wq          = (const float*)d_in[12];
    const float* bq          = (const float*)d_in[13];
    const float* wk          = (const float*)d_in[14];
    const float* bv          = (const float*)d_in[17];
    const float* wv          = (const float*)d_in[16];
    const float* wp          = (const float*)d_in[18];
    const float* bp          = (const float*)d_in[19];
    const float* fw1         = (const float*)d_in[20];
    const float* fb1         = (const float*)d_in[21];
    const float* fw2         = (const float*)d_in[22];
    const float* fb2         = (const float*)d_in[23];
    float* out = (float*)d_out;
    unsigned* wsu = (unsigned*)d_ws;

    prep_weights<<<(WTOT + 511)/512, 512, 0, stream>>>(
        fte_w1, fte_w2, wq, fw1, fw2, wv, wp, wk, wsu);

    decoder_main<<<256, 256, 0, stream>>>(cost_maps, cost_memory, coords1, wsu,
        fte_b1, fte_b2, ln1_g, ln1_b, ln2_g, ln2_b,
        bq, bv, bp, fb1, fb2,
        out + 2*2*512*512);

    upsample_kernel<<<2*64*8, 512, 0, stream>>>(coords1, up_mask, out);
}